// Round 2
// baseline (454.626 us; speedup 1.0000x reference)
//
#include <hip/hip_runtime.h>
#include <hip/hip_bf16.h>

#define HIDDEN 128
#define DEPTH 4
#define INTER 512
#define NSTATE 16
#define DT_RANK 8
#define EPS_RMS 1e-5f
#define MTOK 512            // B*T
#define KIN 150528

typedef __attribute__((ext_vector_type(8))) short bf16x8;
typedef __attribute__((ext_vector_type(4))) float f32x4;

__device__ __forceinline__ unsigned short f2bf(float f) {
  unsigned int u = __builtin_bit_cast(unsigned int, f);
  u += 0x7fffu + ((u >> 16) & 1u);
  return (unsigned short)(u >> 16);
}
__device__ __forceinline__ float silu_f(float x) {
  return x / (1.0f + __expf(-x));
}

// ---------------------------------------------------------------------------
// Projection GEMM v2: grid 256 = (mb 0..7) x (nb 0..1) x (kb 0..15).
// M-tile 64, N-tile 64, k-chunk 256 floats -> 1 KB contiguous DRAM burst per
// row per visit (was 128 B; page-locality was the 1.0 TB/s bottleneck).
// Double-buffered 128 KB LDS, bf16 tiles XOR-swizzled (balanced bank quads).
// Epilogue: plain stores into part[kb] slice (no atomics, no zero-init).
// ---------------------------------------------------------------------------
__global__ __launch_bounds__(512) void proj_gemm(
    const float* __restrict__ x, const float* __restrict__ w,
    float* __restrict__ partial)
{
  const int bid = blockIdx.x;        // 0..255
  const int mb = bid & 7;            // x rows mb*64..  (octet spread over XCDs)
  const int nb = (bid >> 3) & 1;     // w rows nb*64..  (pair shares XCD -> x L2 reuse)
  const int kb = bid >> 4;           // 0..15 k-block
  const int nchunk = 36 + (kb < 12 ? 1 : 0);           // 588 chunks of 256 floats
  const int cb0 = kb * 36 + (kb < 12 ? kb : 12);
  __shared__ unsigned short sm[2][32768];  // [buf][ x:0..16383 | w:16384.. ] 128 KB

  const int tid = threadIdx.x;
  const int lane = tid & 63;
  const int wv = tid >> 6;           // 0..7
  const int wm = wv >> 1;            // 0..3  M-frag
  const int wn = wv & 1;             // 0..1  N-half
  const int fr = lane & 15;
  const int kq = lane >> 4;          // 0..3
  const int rL = tid >> 3;           // 0..63 staging row
  const int cL = tid & 7;            // 0..7  staging col group (float4)

  f32x4 acc[2];
  acc[0] = (f32x4){0.f, 0.f, 0.f, 0.f};
  acc[1] = (f32x4){0.f, 0.f, 0.f, 0.f};

  const float* xrow = x + (size_t)(mb * 64 + rL) * KIN + cL * 4;
  const float* wrow = w + (size_t)(nb * 64 + rL) * KIN + cL * 4;

  float4 rx[8], rw[8];
  {
    const size_t k0 = (size_t)cb0 * 256;
    #pragma unroll
    for (int p = 0; p < 8; ++p) rx[p] = *(const float4*)(xrow + k0 + p * 32);
    #pragma unroll
    for (int p = 0; p < 8; ++p) rw[p] = *(const float4*)(wrow + k0 + p * 32);
  }

  for (int cc = 0; cc < nchunk; ++cc) {
    unsigned short* xs = &sm[cc & 1][0];
    unsigned short* ws_ = &sm[cc & 1][16384];
    const int sb = rL * 512 + cL * 8;     // byte offset (row stride 512 B)
    const int swz = (rL & 7) << 4;        // XOR bits 4-6
    #pragma unroll
    for (int p = 0; p < 8; ++p) {
      ushort4 bx = {f2bf(rx[p].x), f2bf(rx[p].y), f2bf(rx[p].z), f2bf(rx[p].w)};
      *(ushort4*)((char*)xs + ((sb + p * 64) ^ swz)) = bx;
    }
    #pragma unroll
    for (int p = 0; p < 8; ++p) {
      ushort4 bw = {f2bf(rw[p].x), f2bf(rw[p].y), f2bf(rw[p].z), f2bf(rw[p].w)};
      *(ushort4*)((char*)ws_ + ((sb + p * 64) ^ swz)) = bw;
    }
    __syncthreads();
    if (cc + 1 < nchunk) {                // prefetch next 1 KB/row chunk
      const size_t k0 = (size_t)(cb0 + cc + 1) * 256;
      #pragma unroll
      for (int p = 0; p < 8; ++p) rx[p] = *(const float4*)(xrow + k0 + p * 32);
      #pragma unroll
      for (int p = 0; p < 8; ++p) rw[p] = *(const float4*)(wrow + k0 + p * 32);
    }
    const unsigned short* xs2 = &sm[cc & 1][0];
    const unsigned short* ws2 = &sm[cc & 1][16384];
    const int arow = wm * 16 + fr;
    const int br0 = wn * 32 + fr;
    const int aswz = (fr & 7) << 4;
    #pragma unroll
    for (int ks = 0; ks < 8; ++ks) {
      const int kbyte = ks * 64 + kq * 16;
      const bf16x8 a  = *(const bf16x8*)((const char*)xs2 + ((arow * 512 + kbyte) ^ aswz));
      const bf16x8 b0 = *(const bf16x8*)((const char*)ws2 + ((br0 * 512 + kbyte) ^ aswz));
      const bf16x8 b1 = *(const bf16x8*)((const char*)ws2 + (((br0 + 16) * 512 + kbyte) ^ aswz));
      acc[0] = __builtin_amdgcn_mfma_f32_16x16x32_bf16(a, b0, acc[0], 0, 0, 0);
      acc[1] = __builtin_amdgcn_mfma_f32_16x16x32_bf16(a, b1, acc[1], 0, 0, 0);
    }
    __syncthreads();
  }
  // epilogue: 64x64 tile -> part slice kb (plain stores, slice fully tiled)
  float* hp = partial + (size_t)kb * (MTOK * HIDDEN);
  #pragma unroll
  for (int j = 0; j < 2; ++j)
    #pragma unroll
    for (int r = 0; r < 4; ++r) {
      const int row = mb * 64 + wm * 16 + kq * 4 + r;
      const int col = nb * 64 + wn * 32 + j * 16 + fr;
      hp[(size_t)row * HIDDEN + col] = acc[j][r];
    }
}

// ---------------------------------------------------------------------------
// fusedA: [out_proj + residual] + rmsnorm + [in_proj next layer]
// mode 0 FIRST (h from part, 16 slices), 1 MID, 2 LAST (final rms -> dout)
// grid 256 (2 tokens/block), block 512.
// ---------------------------------------------------------------------------
__global__ __launch_bounds__(512) void fusedA(
    int mode,
    const float* __restrict__ part, const float* __restrict__ pb,
    const float* __restrict__ y_g, const float* __restrict__ gate_g,
    float* __restrict__ h_g,
    const float* __restrict__ opw,   // pre-offset (layer l)
    const float* __restrict__ nw,    // pre-offset norm row (or nwf)
    const float* __restrict__ ipw,   // pre-offset (layer l+1)
    float* __restrict__ hs_g, float* __restrict__ gate_out,
    float* __restrict__ dout)
{
  const int m0 = blockIdx.x * 2;
  const int tid = threadIdx.x;     // 0..511
  const int o2 = tid >> 1;         // 0..255
  const int half = tid & 1;
  const int t = o2 >> 7, d = o2 & 127;
  __shared__ float y2[2][512];
  __shared__ float hrow[2][128];
  __shared__ float hn[2][128];

  float hv;
  if (mode == 0) {
    hv = pb[d];
    #pragma unroll
    for (int s = 0; s < 16; ++s)
      hv += part[(size_t)s * (MTOK * HIDDEN) + (size_t)(m0 + t) * 128 + d];
  } else {
    #pragma unroll
    for (int j = 0; j < 2; ++j) {
      const int o = tid + j * 512;
      const int tt = o >> 9, i = o & 511;
      const float yv = y_g[(size_t)(m0 + tt) * 512 + i];
      const float g  = gate_g[(size_t)(m0 + tt) * 512 + i];
      y2[tt][i] = yv * silu_f(g);
    }
    __syncthreads();
    // out_proj: 2 threads per (t,d), k split 256+256
    const float4* yp = (const float4*)(&y2[t][0] + half * 256);
    const float4* wp = (const float4*)(opw + (size_t)d * 512 + half * 256);
    float a0 = 0.f, a1 = 0.f, a2 = 0.f, a3 = 0.f;
    #pragma unroll 8
    for (int kk = 0; kk < 64; ++kk) {
      const float4 yv = yp[kk], wv4 = wp[kk];
      a0 += yv.x * wv4.x; a1 += yv.y * wv4.y;
      a2 += yv.z * wv4.z; a3 += yv.w * wv4.w;
    }
    float a = (a0 + a1) + (a2 + a3);
    a += __shfl_xor(a, 1);          // both halves hold full dot
    hv = h_g[(size_t)(m0 + t) * 128 + d] + a;
  }
  if (mode != 2 && half == 0) h_g[(size_t)(m0 + t) * 128 + d] = hv;
  if (half == 0) hrow[t][d] = hv;
  __syncthreads();
  // rmsnorm (waves 0..3 replicate tokens 0/1; waves 0,1 write)
  {
    const int wvi = tid >> 6, ln = tid & 63;
    const int tt = wvi & 1;
    const float v0 = hrow[tt][ln], v1 = hrow[tt][ln + 64];
    float ss = v0 * v0 + v1 * v1;
    #pragma unroll
    for (int off = 1; off < 64; off <<= 1) ss += __shfl_xor(ss, off);
    const float rr = rsqrtf(ss * (1.0f / 128.0f) + EPS_RMS);
    if (mode == 2) {
      if (wvi < 2) {
        dout[(size_t)(m0 + tt) * 128 + ln]      = v0 * rr * nw[ln];
        dout[(size_t)(m0 + tt) * 128 + ln + 64] = v1 * rr * nw[ln + 64];
      }
      return;
    }
    if (wvi < 2) {
      hn[tt][ln]      = v0 * rr * nw[ln];
      hn[tt][ln + 64] = v1 * rr * nw[ln + 64];
    }
  }
  __syncthreads();
  // in_proj: 2048 outputs, 4 per thread, k=128 from LDS
  #pragma unroll
  for (int j = 0; j < 4; ++j) {
    const int o = tid + j * 512;
    const int tt = o >> 10, e = o & 1023;
    const float4* hp4 = (const float4*)&hn[tt][0];
    const float4* wp4 = (const float4*)(ipw + (size_t)e * 128);
    float a0 = 0.f, a1 = 0.f, a2 = 0.f, a3 = 0.f;
    #pragma unroll
    for (int kk = 0; kk < 32; ++kk) {
      const float4 hvv = hp4[kk], wv4 = wp4[kk];
      a0 += hvv.x * wv4.x; a1 += hvv.y * wv4.y;
      a2 += hvv.z * wv4.z; a3 += hvv.w * wv4.w;
    }
    const float a = (a0 + a1) + (a2 + a3);
    if (e < 512) hs_g[(size_t)(m0 + tt) * 512 + e] = a;
    else         gate_out[(size_t)(m0 + tt) * 512 + (e - 512)] = a;
  }
}

// ---------------------------------------------------------------------------
// convxp: causal conv(k=4)+silu -> uT ; x_proj -> B,C ; dt softplus -> dtT
// grid 256 (2 tokens/block), block 512. hs halo staged in LDS.
// ---------------------------------------------------------------------------
__global__ __launch_bounds__(512) void convxp(
    const float* __restrict__ hs_g, const float* __restrict__ cw,
    const float* __restrict__ cb, const float* __restrict__ xpw,
    const float* __restrict__ dtw, const float* __restrict__ dtb,
    float* __restrict__ uT, float* __restrict__ dtT,
    float* __restrict__ Bm, float* __restrict__ Cm)
{
  const int m0 = blockIdx.x * 2;
  const int b = m0 >> 8, tb0 = m0 & 255;
  const int tid = threadIdx.x;
  __shared__ float hs5[5][512];
  __shared__ float u4[2][512];
  __shared__ float si[2][40];
  for (int o = tid; o < 2560; o += 512) {        // hs rows tb0-3 .. tb0+1
    const int j = o >> 9, i = o & 511;
    const int ct = tb0 - 3 + j;
    hs5[j][i] = (ct >= 0) ? hs_g[((size_t)b * 256 + ct) * 512 + i] : 0.f;
  }
  __syncthreads();
  #pragma unroll
  for (int j = 0; j < 2; ++j) {                  // conv + silu -> u
    const int o = tid + j * 512;
    const int t = o >> 9, i = o & 511;
    const float4 c4v = *(const float4*)(cw + (size_t)i * 4);
    const float s = cb[i] + c4v.x * hs5[t][i] + c4v.y * hs5[t + 1][i]
                          + c4v.z * hs5[t + 2][i] + c4v.w * hs5[t + 3][i];
    const float uu = silu_f(s);
    u4[t][i] = uu;
    uT[((size_t)b * 512 + i) * 256 + tb0 + t] = uu;
  }
  __syncthreads();
  if (tid < 160) {                               // x_proj: 2 threads/output
    const int pid = tid >> 1, half = tid & 1;
    const int t = pid / 40, e = pid % 40;
    const float4* up = (const float4*)(&u4[t][0] + half * 256);
    const float4* wp = (const float4*)(xpw + (size_t)e * 512 + half * 256);
    float a0 = 0.f, a1 = 0.f, a2 = 0.f, a3 = 0.f;
    #pragma unroll 8
    for (int kk = 0; kk < 64; ++kk) {
      const float4 uv = up[kk], wv4 = wp[kk];
      a0 += uv.x * wv4.x; a1 += uv.y * wv4.y;
      a2 += uv.z * wv4.z; a3 += uv.w * wv4.w;
    }
    float a = (a0 + a1) + (a2 + a3);
    a += __shfl_xor(a, 1);
    if (half == 0) si[t][e] = a;
  }
  __syncthreads();
  if (tid < 64) {                                // B, C rows
    const int t = tid >> 5, q = tid & 31;
    if (q < 16) Bm[(size_t)(m0 + t) * 16 + q] = si[t][8 + q];
    else        Cm[(size_t)(m0 + t) * 16 + (q - 16)] = si[t][24 + (q - 16)];
  }
  #pragma unroll
  for (int j = 0; j < 2; ++j) {                  // dt softplus -> dtT
    const int o = tid + j * 512;
    const int i = o >> 1, t = o & 1;
    float a0 = dtb[i];
    const float* dr = dtw + (size_t)i * 8;
    #pragma unroll
    for (int r = 0; r < 8; ++r) a0 += si[t][r] * dr[r];
    const float sp = (a0 > 20.f) ? a0 : log1pf(__expf(a0));
    dtT[((size_t)b * 512 + i) * 256 + tb0 + t] = sp;
  }
}

// ---------------------------------------------------------------------------
// scan_k: chunked SSM scan. grid 1024 (one (b,i) per block), block 256
// (16 chunks x 16 states). uT/dtT rows coalesced; B/C contiguous.
// ---------------------------------------------------------------------------
__global__ __launch_bounds__(256) void scan_k(
    const float* __restrict__ uT, const float* __restrict__ dtT,
    const float* __restrict__ Bm, const float* __restrict__ Cm,
    const float* __restrict__ Alog, const float* __restrict__ Dssm,
    float* __restrict__ y_g)
{
  const int blk = blockIdx.x;       // 0..1023
  const int b = blk >> 9, i = blk & 511;
  const int tid = threadIdx.x;
  __shared__ float dt_r[256], u_r[256];
  __shared__ float B_l[256][17], C_l[256][17];
  __shared__ float e_l[16][17], P_l[16][17];
  dt_r[tid] = dtT[((size_t)b * 512 + i) * 256 + tid];
  u_r[tid]  = uT[((size_t)b * 512 + i) * 256 + tid];
  #pragma unroll
  for (int j = 0; j < 16; ++j) {
    const int o = tid + j * 256;
    B_l[o >> 4][o & 15] = Bm[(size_t)b * 4096 + o];
    C_l[o >> 4][o & 15] = Cm[(size_t)b * 4096 + o];
  }
  __syncthreads();
  const int c = tid >> 4, n = tid & 15;
  const float Av = -__expf(Alog[(size_t)i * 16 + n]);
  const float Dv = Dssm[i];
  float aj[16], xj[16];
  float s = 0.f, P = 1.f;
  #pragma unroll
  for (int j = 0; j < 16; ++j) {    // pass 1: local scan from 0
    const int t = c * 16 + j;
    const float dtv = dt_r[t];
    const float a = __expf(Av * dtv);
    const float xx = dtv * B_l[t][n] * u_r[t];
    aj[j] = a; xj[j] = xx;
    s = a * s + xx; P *= a;
  }
  e_l[c][n] = s; P_l[c][n] = P;
  __syncthreads();
  float s0 = 0.f;                   // stitch chunk prefixes
  for (int cc = 0; cc < c; ++cc)
    s0 = P_l[cc][n] * s0 + e_l[cc][n];
  s = s0;
  #pragma unroll
  for (int j = 0; j < 16; ++j) {    // pass 2: replay with true state
    const int t = c * 16 + j;
    s = aj[j] * s + xj[j];
    float p = s * C_l[t][n];
    p += __shfl_xor(p, 1); p += __shfl_xor(p, 2);
    p += __shfl_xor(p, 4); p += __shfl_xor(p, 8);
    if (n == 0)
      y_g[((size_t)b * 256 + t) * 512 + i] = p + u_r[t] * Dv;
  }
}

extern "C" void kernel_launch(void* const* d_in, const int* in_sizes, int n_in,
                              void* d_out, int out_size, void* d_ws, size_t ws_size,
                              hipStream_t stream)
{
  (void)in_sizes; (void)n_in; (void)out_size; (void)ws_size;
  const float* x    = (const float*)d_in[0];
  const float* pw   = (const float*)d_in[1];
  const float* pb   = (const float*)d_in[2];
  const float* ipw  = (const float*)d_in[3];
  const float* cw   = (const float*)d_in[4];
  const float* cb   = (const float*)d_in[5];
  const float* xpw  = (const float*)d_in[6];
  const float* dtw  = (const float*)d_in[7];
  const float* dtb  = (const float*)d_in[8];
  const float* Alog = (const float*)d_in[9];
  const float* Dssm = (const float*)d_in[10];
  const float* opw  = (const float*)d_in[11];
  const float* nw   = (const float*)d_in[12];
  const float* nwf  = (const float*)d_in[13];
  float* out = (float*)d_out;

  float* ws   = (float*)d_ws;                 // ~9.8 MB scratch
  float* part = ws;                           // 16 * 65536 (written, not accumulated)
  float* h    = part + 16 * 65536;            // 65536
  float* hs   = h + 65536;                    // 262144
  float* gate = hs + 262144;                  // 262144
  float* uT   = gate + 262144;                // 262144
  float* dtT  = uT + 262144;                  // 262144
  float* Bm   = dtT + 262144;                 // 8192
  float* Cm   = Bm + 8192;                    // 8192
  float* y    = Cm + 8192;                    // 262144

  proj_gemm<<<dim3(256), 512, 0, stream>>>(x, pw, part);

  // first: h from part + rms + in_proj(l=0)
  fusedA<<<dim3(256), 512, 0, stream>>>(0, part, pb, nullptr, nullptr, h,
                                        nullptr, nw, ipw, hs, gate, nullptr);
  for (int l = 0; l < DEPTH; ++l) {
    convxp<<<dim3(256), 512, 0, stream>>>(
        hs, cw + (size_t)l * 2048, cb + (size_t)l * 512,
        xpw + (size_t)l * 40 * 512, dtw + (size_t)l * 512 * 8,
        dtb + (size_t)l * 512, uT, dtT, Bm, Cm);
    scan_k<<<dim3(1024), 256, 0, stream>>>(
        uT, dtT, Bm, Cm, Alog + (size_t)l * 512 * 16, Dssm + (size_t)l * 512, y);
    if (l < DEPTH - 1)
      fusedA<<<dim3(256), 512, 0, stream>>>(1, nullptr, nullptr, y, gate, h,
          opw + (size_t)l * 128 * 512, nw + (size_t)(l + 1) * 128,
          ipw + (size_t)(l + 1) * 1024 * 128, hs, gate, nullptr);
    else
      fusedA<<<dim3(256), 512, 0, stream>>>(2, nullptr, nullptr, y, gate, h,
          opw + (size_t)l * 128 * 512, nwf, nullptr, nullptr, nullptr, out);
  }
}

// Round 3
// 415.454 us; speedup vs baseline: 1.0943x; 1.0943x over previous
//
#include <hip/hip_runtime.h>
#include <hip/hip_bf16.h>

#define HIDDEN 128
#define DEPTH 4
#define INTER 512
#define NSTATE 16
#define DT_RANK 8
#define EPS_RMS 1e-5f
#define MTOK 512            // B*T
#define KIN 150528

typedef __attribute__((ext_vector_type(8))) short bf16x8;
typedef __attribute__((ext_vector_type(4))) float f32x4;

__device__ __forceinline__ unsigned short f2bf(float f) {
  unsigned int u = __builtin_bit_cast(unsigned int, f);
  u += 0x7fffu + ((u >> 16) & 1u);
  return (unsigned short)(u >> 16);
}
__device__ __forceinline__ float silu_f(float x) {
  return x / (1.0f + __expf(-x));
}

// ---------------------------------------------------------------------------
// zero_part: 4 MB partial buffer zero (1024 x 256 x float4).
// ---------------------------------------------------------------------------
__global__ __launch_bounds__(256) void zero_part(float* __restrict__ p)
{
  const size_t i = (size_t)blockIdx.x * 256 + threadIdx.x;
  ((float4*)p)[i] = (float4){0.f, 0.f, 0.f, 0.f};
}

// ---------------------------------------------------------------------------
// Projection GEMM v3: zero-duplication tiling.
// grid 256 = mb(4) x kb(64); NT=128 (full N, x read ONCE), MT=128
// (w read 4x, L2-served: the 4 mb-blocks of each kb are XCD-clustered via
// bid decode kb=(bid&7)+(bid>>5)*8). K-chunk 128 floats -> 512-B bursts.
// LDS 64 KB bf16 single-buffer, register prefetch (v2-proven loop shape).
// Swizzle: phys = logical ^ ((row&7)<<4) at BOTH write and read -> no
// excess bank conflicts (hand-verified: reads 4 words/bank/wave = minimum).
// Epilogue: atomicAdd into 16 slices (ws stays ~10 MB, v1-proven scale).
// ---------------------------------------------------------------------------
__global__ __launch_bounds__(512) void proj_gemm(
    const float* __restrict__ x, const float* __restrict__ w,
    float* __restrict__ partial)
{
  const int bid = blockIdx.x;          // 0..255
  const int mb = (bid >> 3) & 3;       // 0..3  (M-tile of 128 rows)
  const int kb = (bid & 7) + (bid >> 5) * 8;   // 0..63 (XCD-clustered)
  // 1176 chunks of 128 floats; kb<24 -> 19 chunks, else 18
  const int nchunk = 18 + (kb < 24 ? 1 : 0);
  const int c0 = kb * 18 + (kb < 24 ? kb : 24);

  __shared__ char sm[256 * 256];       // 256 rows (x:0-127, w:128-255) x 256 B bf16

  const int tid = threadIdx.x;
  const int lane = tid & 63;
  const int wv = tid >> 6;             // 0..7
  const int wm2 = wv >> 2;             // 0..1  M-half (64 rows)
  const int wn4 = wv & 3;              // 0..3  N-quarter (32 cols)
  const int fr = lane & 15;
  const int kq = lane >> 4;            // 0..3
  const int l31 = lane & 31;
  const int rpar = lane >> 5;          // 0/1 row parity within staging pair

  // staging: wave wv owns LDS rows [wv*32, wv*32+32); waves 0-3 = x, 4-7 = w
  const float* gptr = (wv < 4)
      ? (x + (size_t)(mb * 128 + wv * 32 + rpar) * KIN + l31 * 4)
      : (w + (size_t)((wv - 4) * 32 + rpar) * KIN + l31 * 4);

  f32x4 acc[4][2];
  #pragma unroll
  for (int mi = 0; mi < 4; ++mi) {
    acc[mi][0] = (f32x4){0.f, 0.f, 0.f, 0.f};
    acc[mi][1] = (f32x4){0.f, 0.f, 0.f, 0.f};
  }

  float4 rv[16];
  {
    const float* base = gptr + (size_t)c0 * 128;
    #pragma unroll
    for (int j = 0; j < 16; ++j)
      rv[j] = *(const float4*)(base + (size_t)(j * 2) * KIN);
  }

  for (int cc = 0; cc < nchunk; ++cc) {
    // stage regs -> LDS bf16 (swizzled write)
    #pragma unroll
    for (int j = 0; j < 16; ++j) {
      const int r = wv * 32 + j * 2 + rpar;
      const int phys = (l31 * 8) ^ ((r & 7) << 4);
      ushort4 bq = {f2bf(rv[j].x), f2bf(rv[j].y), f2bf(rv[j].z), f2bf(rv[j].w)};
      *(ushort4*)(sm + r * 256 + phys) = bq;
    }
    __syncthreads();
    if (cc + 1 < nchunk) {             // prefetch next chunk (overlaps compute)
      const float* base = gptr + (size_t)(c0 + cc + 1) * 128;
      #pragma unroll
      for (int j = 0; j < 16; ++j)
        rv[j] = *(const float4*)(base + (size_t)(j * 2) * KIN);
    }
    // compute: 4 k-steps of 32
    #pragma unroll
    for (int ks = 0; ks < 4; ++ks) {
      const int log = ks * 64 + kq * 16;
      bf16x8 a[4];
      #pragma unroll
      for (int mi = 0; mi < 4; ++mi) {
        const int row = wm2 * 64 + mi * 16 + fr;
        a[mi] = *(const bf16x8*)(sm + row * 256 + (log ^ ((row & 7) << 4)));
      }
      #pragma unroll
      for (int ni = 0; ni < 2; ++ni) {
        const int row = 128 + wn4 * 32 + ni * 16 + fr;
        const bf16x8 b = *(const bf16x8*)(sm + row * 256 + (log ^ ((row & 7) << 4)));
        #pragma unroll
        for (int mi = 0; mi < 4; ++mi)
          acc[mi][ni] = __builtin_amdgcn_mfma_f32_16x16x32_bf16(a[mi], b, acc[mi][ni], 0, 0, 0);
      }
    }
    __syncthreads();
  }
  // epilogue: atomic accumulate into slice (kb & 15)
  float* hp = partial + (size_t)(kb & 15) * (MTOK * HIDDEN);
  #pragma unroll
  for (int mi = 0; mi < 4; ++mi)
    #pragma unroll
    for (int ni = 0; ni < 2; ++ni)
      #pragma unroll
      for (int r = 0; r < 4; ++r) {
        const int row = mb * 128 + wm2 * 64 + mi * 16 + kq * 4 + r;
        const int col = wn4 * 32 + ni * 16 + fr;
        atomicAdd(hp + (size_t)row * HIDDEN + col, acc[mi][ni][r]);
      }
}

// ---------------------------------------------------------------------------
// fusedA: [out_proj + residual] + rmsnorm + [in_proj next layer]
// mode 0 FIRST (h from part, 16 slices), 1 MID, 2 LAST (final rms -> dout)
// grid 256 (2 tokens/block), block 512.
// ---------------------------------------------------------------------------
__global__ __launch_bounds__(512) void fusedA(
    int mode,
    const float* __restrict__ part, const float* __restrict__ pb,
    const float* __restrict__ y_g, const float* __restrict__ gate_g,
    float* __restrict__ h_g,
    const float* __restrict__ opw,   // pre-offset (layer l)
    const float* __restrict__ nw,    // pre-offset norm row (or nwf)
    const float* __restrict__ ipw,   // pre-offset (layer l+1)
    float* __restrict__ hs_g, float* __restrict__ gate_out,
    float* __restrict__ dout)
{
  const int m0 = blockIdx.x * 2;
  const int tid = threadIdx.x;     // 0..511
  const int o2 = tid >> 1;         // 0..255
  const int half = tid & 1;
  const int t = o2 >> 7, d = o2 & 127;
  __shared__ float y2[2][512];
  __shared__ float hrow[2][128];
  __shared__ float hn[2][128];

  float hv;
  if (mode == 0) {
    hv = pb[d];
    #pragma unroll
    for (int s = 0; s < 16; ++s)
      hv += part[(size_t)s * (MTOK * HIDDEN) + (size_t)(m0 + t) * 128 + d];
  } else {
    #pragma unroll
    for (int j = 0; j < 2; ++j) {
      const int o = tid + j * 512;
      const int tt = o >> 9, i = o & 511;
      const float yv = y_g[(size_t)(m0 + tt) * 512 + i];
      const float g  = gate_g[(size_t)(m0 + tt) * 512 + i];
      y2[tt][i] = yv * silu_f(g);
    }
    __syncthreads();
    // out_proj: 2 threads per (t,d), k split 256+256
    const float4* yp = (const float4*)(&y2[t][0] + half * 256);
    const float4* wp = (const float4*)(opw + (size_t)d * 512 + half * 256);
    float a0 = 0.f, a1 = 0.f, a2 = 0.f, a3 = 0.f;
    #pragma unroll 8
    for (int kk = 0; kk < 64; ++kk) {
      const float4 yv = yp[kk], wv4 = wp[kk];
      a0 += yv.x * wv4.x; a1 += yv.y * wv4.y;
      a2 += yv.z * wv4.z; a3 += yv.w * wv4.w;
    }
    float a = (a0 + a1) + (a2 + a3);
    a += __shfl_xor(a, 1);          // both halves hold full dot
    hv = h_g[(size_t)(m0 + t) * 128 + d] + a;
  }
  if (mode != 2 && half == 0) h_g[(size_t)(m0 + t) * 128 + d] = hv;
  if (half == 0) hrow[t][d] = hv;
  __syncthreads();
  // rmsnorm (waves 0..3 replicate tokens 0/1; waves 0,1 write)
  {
    const int wvi = tid >> 6, ln = tid & 63;
    const int tt = wvi & 1;
    const float v0 = hrow[tt][ln], v1 = hrow[tt][ln + 64];
    float ss = v0 * v0 + v1 * v1;
    #pragma unroll
    for (int off = 1; off < 64; off <<= 1) ss += __shfl_xor(ss, off);
    const float rr = rsqrtf(ss * (1.0f / 128.0f) + EPS_RMS);
    if (mode == 2) {
      if (wvi < 2) {
        dout[(size_t)(m0 + tt) * 128 + ln]      = v0 * rr * nw[ln];
        dout[(size_t)(m0 + tt) * 128 + ln + 64] = v1 * rr * nw[ln + 64];
      }
      return;
    }
    if (wvi < 2) {
      hn[tt][ln]      = v0 * rr * nw[ln];
      hn[tt][ln + 64] = v1 * rr * nw[ln + 64];
    }
  }
  __syncthreads();
  // in_proj: 2048 outputs, 4 per thread, k=128 from LDS
  #pragma unroll
  for (int j = 0; j < 4; ++j) {
    const int o = tid + j * 512;
    const int tt = o >> 10, e = o & 1023;
    const float4* hp4 = (const float4*)&hn[tt][0];
    const float4* wp4 = (const float4*)(ipw + (size_t)e * 128);
    float a0 = 0.f, a1 = 0.f, a2 = 0.f, a3 = 0.f;
    #pragma unroll
    for (int kk = 0; kk < 32; ++kk) {
      const float4 hvv = hp4[kk], wv4 = wp4[kk];
      a0 += hvv.x * wv4.x; a1 += hvv.y * wv4.y;
      a2 += hvv.z * wv4.z; a3 += hvv.w * wv4.w;
    }
    const float a = (a0 + a1) + (a2 + a3);
    if (e < 512) hs_g[(size_t)(m0 + tt) * 512 + e] = a;
    else         gate_out[(size_t)(m0 + tt) * 512 + (e - 512)] = a;
  }
}

// ---------------------------------------------------------------------------
// convxp: causal conv(k=4)+silu -> uT ; x_proj -> B,C ; dt softplus -> dtT
// grid 256 (2 tokens/block), block 512. hs halo staged in LDS.
// ---------------------------------------------------------------------------
__global__ __launch_bounds__(512) void convxp(
    const float* __restrict__ hs_g, const float* __restrict__ cw,
    const float* __restrict__ cb, const float* __restrict__ xpw,
    const float* __restrict__ dtw, const float* __restrict__ dtb,
    float* __restrict__ uT, float* __restrict__ dtT,
    float* __restrict__ Bm, float* __restrict__ Cm)
{
  const int m0 = blockIdx.x * 2;
  const int b = m0 >> 8, tb0 = m0 & 255;
  const int tid = threadIdx.x;
  __shared__ float hs5[5][512];
  __shared__ float u4[2][512];
  __shared__ float si[2][40];
  for (int o = tid; o < 2560; o += 512) {        // hs rows tb0-3 .. tb0+1
    const int j = o >> 9, i = o & 511;
    const int ct = tb0 - 3 + j;
    hs5[j][i] = (ct >= 0) ? hs_g[((size_t)b * 256 + ct) * 512 + i] : 0.f;
  }
  __syncthreads();
  #pragma unroll
  for (int j = 0; j < 2; ++j) {                  // conv + silu -> u
    const int o = tid + j * 512;
    const int t = o >> 9, i = o & 511;
    const float4 c4v = *(const float4*)(cw + (size_t)i * 4);
    const float s = cb[i] + c4v.x * hs5[t][i] + c4v.y * hs5[t + 1][i]
                          + c4v.z * hs5[t + 2][i] + c4v.w * hs5[t + 3][i];
    const float uu = silu_f(s);
    u4[t][i] = uu;
    uT[((size_t)b * 512 + i) * 256 + tb0 + t] = uu;
  }
  __syncthreads();
  if (tid < 160) {                               // x_proj: 2 threads/output
    const int pid = tid >> 1, half = tid & 1;
    const int t = pid / 40, e = pid % 40;
    const float4* up = (const float4*)(&u4[t][0] + half * 256);
    const float4* wp = (const float4*)(xpw + (size_t)e * 512 + half * 256);
    float a0 = 0.f, a1 = 0.f, a2 = 0.f, a3 = 0.f;
    #pragma unroll 8
    for (int kk = 0; kk < 64; ++kk) {
      const float4 uv = up[kk], wv4 = wp[kk];
      a0 += uv.x * wv4.x; a1 += uv.y * wv4.y;
      a2 += uv.z * wv4.z; a3 += uv.w * wv4.w;
    }
    float a = (a0 + a1) + (a2 + a3);
    a += __shfl_xor(a, 1);
    if (half == 0) si[t][e] = a;
  }
  __syncthreads();
  if (tid < 64) {                                // B, C rows
    const int t = tid >> 5, q = tid & 31;
    if (q < 16) Bm[(size_t)(m0 + t) * 16 + q] = si[t][8 + q];
    else        Cm[(size_t)(m0 + t) * 16 + (q - 16)] = si[t][24 + (q - 16)];
  }
  #pragma unroll
  for (int j = 0; j < 2; ++j) {                  // dt softplus -> dtT
    const int o = tid + j * 512;
    const int i = o >> 1, t = o & 1;
    float a0 = dtb[i];
    const float* dr = dtw + (size_t)i * 8;
    #pragma unroll
    for (int r = 0; r < 8; ++r) a0 += si[t][r] * dr[r];
    const float sp = (a0 > 20.f) ? a0 : log1pf(__expf(a0));
    dtT[((size_t)b * 512 + i) * 256 + tb0 + t] = sp;
  }
}

// ---------------------------------------------------------------------------
// scan_k: chunked SSM scan. grid 1024 (one (b,i) per block), block 256
// (16 chunks x 16 states). uT/dtT rows coalesced; B/C contiguous.
// ---------------------------------------------------------------------------
__global__ __launch_bounds__(256) void scan_k(
    const float* __restrict__ uT, const float* __restrict__ dtT,
    const float* __restrict__ Bm, const float* __restrict__ Cm,
    const float* __restrict__ Alog, const float* __restrict__ Dssm,
    float* __restrict__ y_g)
{
  const int blk = blockIdx.x;       // 0..1023
  const int b = blk >> 9, i = blk & 511;
  const int tid = threadIdx.x;
  __shared__ float dt_r[256], u_r[256];
  __shared__ float B_l[256][17], C_l[256][17];
  __shared__ float e_l[16][17], P_l[16][17];
  dt_r[tid] = dtT[((size_t)b * 512 + i) * 256 + tid];
  u_r[tid]  = uT[((size_t)b * 512 + i) * 256 + tid];
  #pragma unroll
  for (int j = 0; j < 16; ++j) {
    const int o = tid + j * 256;
    B_l[o >> 4][o & 15] = Bm[(size_t)b * 4096 + o];
    C_l[o >> 4][o & 15] = Cm[(size_t)b * 4096 + o];
  }
  __syncthreads();
  const int c = tid >> 4, n = tid & 15;
  const float Av = -__expf(Alog[(size_t)i * 16 + n]);
  const float Dv = Dssm[i];
  float aj[16], xj[16];
  float s = 0.f, P = 1.f;
  #pragma unroll
  for (int j = 0; j < 16; ++j) {    // pass 1: local scan from 0
    const int t = c * 16 + j;
    const float dtv = dt_r[t];
    const float a = __expf(Av * dtv);
    const float xx = dtv * B_l[t][n] * u_r[t];
    aj[j] = a; xj[j] = xx;
    s = a * s + xx; P *= a;
  }
  e_l[c][n] = s; P_l[c][n] = P;
  __syncthreads();
  float s0 = 0.f;                   // stitch chunk prefixes
  for (int cc = 0; cc < c; ++cc)
    s0 = P_l[cc][n] * s0 + e_l[cc][n];
  s = s0;
  #pragma unroll
  for (int j = 0; j < 16; ++j) {    // pass 2: replay with true state
    const int t = c * 16 + j;
    s = aj[j] * s + xj[j];
    float p = s * C_l[t][n];
    p += __shfl_xor(p, 1); p += __shfl_xor(p, 2);
    p += __shfl_xor(p, 4); p += __shfl_xor(p, 8);
    if (n == 0)
      y_g[((size_t)b * 256 + t) * 512 + i] = p + u_r[t] * Dv;
  }
}

extern "C" void kernel_launch(void* const* d_in, const int* in_sizes, int n_in,
                              void* d_out, int out_size, void* d_ws, size_t ws_size,
                              hipStream_t stream)
{
  (void)in_sizes; (void)n_in; (void)out_size; (void)ws_size;
  const float* x    = (const float*)d_in[0];
  const float* pw   = (const float*)d_in[1];
  const float* pb   = (const float*)d_in[2];
  const float* ipw  = (const float*)d_in[3];
  const float* cw   = (const float*)d_in[4];
  const float* cb   = (const float*)d_in[5];
  const float* xpw  = (const float*)d_in[6];
  const float* dtw  = (const float*)d_in[7];
  const float* dtb  = (const float*)d_in[8];
  const float* Alog = (const float*)d_in[9];
  const float* Dssm = (const float*)d_in[10];
  const float* opw  = (const float*)d_in[11];
  const float* nw   = (const float*)d_in[12];
  const float* nwf  = (const float*)d_in[13];
  float* out = (float*)d_out;

  float* ws   = (float*)d_ws;                 // ~10 MB scratch
  float* part = ws;                           // 16 * 65536 (atomic-accumulated)
  float* h    = part + 16 * 65536;            // 65536
  float* hs   = h + 65536;                    // 262144
  float* gate = hs + 262144;                  // 262144
  float* uT   = gate + 262144;                // 262144
  float* dtT  = uT + 262144;                  // 262144
  float* Bm   = dtT + 262144;                 // 8192
  float* Cm   = Bm + 8192;                    // 8192
  float* y    = Cm + 8192;                    // 262144

  zero_part<<<dim3(1024), 256, 0, stream>>>(part);
  proj_gemm<<<dim3(256), 512, 0, stream>>>(x, pw, part);

  // first: h from part + rms + in_proj(l=0)
  fusedA<<<dim3(256), 512, 0, stream>>>(0, part, pb, nullptr, nullptr, h,
                                        nullptr, nw, ipw, hs, gate, nullptr);
  for (int l = 0; l < DEPTH; ++l) {
    convxp<<<dim3(256), 512, 0, stream>>>(
        hs, cw + (size_t)l * 2048, cb + (size_t)l * 512,
        xpw + (size_t)l * 40 * 512, dtw + (size_t)l * 512 * 8,
        dtb + (size_t)l * 512, uT, dtT, Bm, Cm);
    scan_k<<<dim3(1024), 256, 0, stream>>>(
        uT, dtT, Bm, Cm, Alog + (size_t)l * 512 * 16, Dssm + (size_t)l * 512, y);
    if (l < DEPTH - 1)
      fusedA<<<dim3(256), 512, 0, stream>>>(1, nullptr, nullptr, y, gate, h,
          opw + (size_t)l * 128 * 512, nw + (size_t)(l + 1) * 128,
          ipw + (size_t)(l + 1) * 1024 * 128, hs, gate, nullptr);
    else
      fusedA<<<dim3(256), 512, 0, stream>>>(2, nullptr, nullptr, y, gate, h,
          opw + (size_t)l * 128 * 512, nwf, nullptr, nullptr, nullptr, out);
  }
}